// Round 13
// baseline (124.134 us; speedup 1.0000x reference)
//
#include <hip/hip_runtime.h>

#define B_ 4096
#define C_ 128
#define D_ 768
#define NT 1024
#define NW (NT/64)                  // 16 waves
#define M_MAX 96
#define P_MAX (M_MAX*(M_MAX-1)/2)   // 4560
#define CK 128
#define NCH (D_/CK)                 // 6
#define SROW 132                    // floats; bank(row r) = 4r mod 32 -> 8-bank spread
#define TILE_F (M_MAX*SROW)         // 12672 floats per buffer
#define LM2 2                       // (fallback kernel only)
#define RC 127                      // row code meaning "cvec"
#define SPT ((M_MAX*(CK/4) + NT - 1)/NT)    // 3 staging float4s per thread
#define LCAP 64                     // in-bin candidate list cap (expected ~7)
// ws layout: [0,512) lossv | [512,1024) wv | [1024,1028) flags[0] |
// [2048,2560) wsM (C ints) | [2560,+C*M_MAX*4) wsG |
// [65536,+C*P_MAX*4) wsS | then C*M_MAX*4 wsE
#define WS_MOFF 2048u
#define WS_GOFF 2560u
#define WS_SOFF 65536u
#define WS_SBYTES ((size_t)C_ * P_MAX * 4u)
#define WS_NEED (WS_SOFF + WS_SBYTES + (size_t)C_ * M_MAX * 4u)

__device__ __forceinline__ float wave_red(float v){
#pragma unroll
  for (int o = 32; o > 0; o >>= 1) v += __shfl_down(v, o, 64);
  return v;
}
__device__ __forceinline__ float clamp1(float x){ return fminf(fmaxf(x, -1.f), 1.f); }
__device__ __forceinline__ unsigned rotl32(unsigned x, int r){ return (x << r) | (x >> (32 - r)); }
__device__ __forceinline__ float dot4(float4 a, float4 b){
  return fmaf(a.x, b.x, fmaf(a.y, b.y, fmaf(a.z, b.z, a.w * b.w)));
}

// jax.random.uniform(jax.random.key(1),(B,B)) element n: Threefry-2x32 key (0,1),
// counters split in halves. Bit-exact (verified: absmax 0.0 across all rounds).
__device__ float rand_ij(unsigned n){
  const unsigned half = (unsigned)B_ * (unsigned)B_ / 2u;
  unsigned c0, c1; bool hi;
  if (n < half){ c0 = n; c1 = n + half; hi = false; }
  else         { c0 = n - half; c1 = n; hi = true; }
  const unsigned K0 = 0u, K1 = 1u, K2 = 0x1BD11BDBu;
  unsigned x0 = c0 + K0, x1 = c1 + K1;
#define TFR(r) { x0 += x1; x1 = rotl32(x1, (r)); x1 ^= x0; }
  TFR(13) TFR(15) TFR(26) TFR(6)  x0 += K1; x1 += K2 + 1u;
  TFR(17) TFR(29) TFR(16) TFR(24) x0 += K2; x1 += K0 + 2u;
  TFR(13) TFR(15) TFR(26) TFR(6)  x0 += K0; x1 += K1 + 3u;
  TFR(17) TFR(29) TFR(16) TFR(24) x0 += K1; x1 += K2 + 4u;
  TFR(13) TFR(15) TFR(26) TFR(6)  x0 += K2; x1 += K0 + 5u;
#undef TFR
  unsigned bits = hi ? x1 : x0;
  return __uint_as_float((bits >> 9) | 0x3F800000u) - 1.0f;
}

// p -> (a,b), a<b<m, row-major upper-tri. before(a) = a*(2m-1-a)/2.
__device__ __forceinline__ void decode_pair(int p, int m, int* a_, int* b_){
  float fm = (float)(2*m - 1);
  int a = (int)((fm - sqrtf(fm*fm - 8.0f*(float)p)) * 0.5f);
  a = max(0, min(a, m - 2));
  while (a > 0 && (a*(2*m - 1 - a))/2 > p) --a;
  while (((a + 1)*(2*m - 2 - a))/2 <= p) ++a;
  *a_ = a;
  *b_ = a + 1 + (p - (a*(2*m - 1 - a))/2);
}

// ---- slow-path helpers (unreachable: all classes m<=96; insurance only) ----
__device__ float dotg(const float* x, const float* y){
  float s = 0.f;
  for (int k = 0; k < D_; ++k) s = fmaf(x[k], y[k], s);
  return s;
}
__device__ float S_pair_g(const float* feat, int ga, int gb){
  const float* ra = feat + (size_t)ga * D_;
  const float* rb = feat + (size_t)gb * D_;
  float d = dotg(ra, rb);
  float na = 1.f / fmaxf(sqrtf(dotg(ra, ra)), 1e-12f);
  float nb = 1.f / fmaxf(sqrtf(dotg(rb, rb)), 1e-12f);
  return d * na * nb;
}

// ==== KERNEL 1: gram producer, 2 sibling blocks per class (grid 256).
// CONTIGUOUS unit split (R12 lesson: parity split leaves 32 active lanes in
// every wave -> wave ds_read count unchanged). Per-sibling compact unit list:
// [my half of strict off-diag pairs | all diag units | all ec units] — dense
// active threads, inactive waves skip the gram body entirely. Full-D fold per
// dot (bit-exact). Publishes m, gid, normalized S, ecs. Stream-ordered. ====
__global__ __launch_bounds__(NT) void k_gram(
    const float* __restrict__ feat, const float* __restrict__ cent,
    const int* __restrict__ labels,
    int* __restrict__ wsM, int* __restrict__ wsG,
    float* __restrict__ wsS, float* __restrict__ wsE)
{
  const int c  = blockIdx.x >> 1;
  const int kh = blockIdx.x & 1;
  const int tid = threadIdx.x;

  __shared__ int   gid_s[M_MAX];
  __shared__ int   mcount;
  __shared__ __align__(16) float tile[2 * TILE_F];     // 101376 B, double-buffered
  __shared__ __align__(16) float cvec[2][CK];
  __shared__ float selfs[M_MAX];
  __shared__ float ecs[M_MAX];
  __shared__ float cn_sh;

  // ---- phase A: collect members of class c ----
  if (tid == 0) mcount = 0;
  __syncthreads();
  {
    const int4* lab4 = (const int4*)labels;
    for (int i = tid; i < B_ / 4; i += NT){
      int4 L = lab4[i];
      int base = i << 2;
      if (L.x == c){ int p = atomicAdd(&mcount, 1); if (p < M_MAX) gid_s[p] = base; }
      if (L.y == c){ int p = atomicAdd(&mcount, 1); if (p < M_MAX) gid_s[p] = base + 1; }
      if (L.z == c){ int p = atomicAdd(&mcount, 1); if (p < M_MAX) gid_s[p] = base + 2; }
      if (L.w == c){ int p = atomicAdd(&mcount, 1); if (p < M_MAX) gid_s[p] = base + 3; }
    }
  }
  __syncthreads();
  const int m = mcount;
  if (kh == 0 && tid == 0) wsM[c] = m;    // always publish m (k_sel depends)
  if (m < 2 || m > M_MAX) return;         // k_sel handles these cases
  if (kh == 0 && tid < m) wsG[c * M_MAX + tid] = gid_s[tid];

  const int nst = m * (CK / 4);
  float* wsc = wsS + (size_t)c * P_MAX;

  // ---- compact per-sibling units ----
  // h=ceil(m/2); strict off-diag pairs (ta<tb over h row-blocks): nOff.
  // Sibling kh takes q in [qbase, qbase+qcnt) contiguously; then h diag
  // units (rows {d,d+h}); then hec ec units. U <= 564+48+49 = 661 < NT.
  const int h    = (m + 1) >> 1;
  const int nOff = h * (h - 1) / 2;
  const int half0 = (nOff + 1) >> 1;
  const int qbase = (kh == 0) ? 0 : half0;
  const int qcnt  = (kh == 0) ? half0 : (nOff - half0);
  const int hec  = (m + 2) >> 1;
  const int U    = qcnt + h + hec;

  int uty = -1;                 // 0=off-diag pair, 1=diag, 2=ec
  int ta_ = 0, tb_ = 0, g_ = 0;
  int rc0 = 0, rc1 = 0, rc2 = 0, rc3 = 0;
  if (tid < U){
    if (tid < qcnt){
      int q = qbase + tid;
      int ta = 0;               // strict-upper before(ta) = ta*(2h-1-ta)/2
      while ((ta + 1) * (2*h - 2 - ta) / 2 <= q) ++ta;
      int tb = ta + 1 + (q - (ta * (2*h - 1 - ta)) / 2);
      uty = 0; ta_ = ta; tb_ = tb;
      rc0 = ta; rc1 = ta + h; rc2 = tb; rc3 = tb + h;   // rows <= 2h-1 <= 96
    } else if (tid < qcnt + h){
      int d = tid - qcnt;
      uty = 1; ta_ = d;
      rc0 = d; rc1 = d + h; rc2 = d; rc3 = d + h;
    } else {
      int g = tid - qcnt - h;
      int l1 = g + hec;
      uty = 2; g_ = g;
      rc0 = g;
      rc1 = (l1 == m) ? RC : ((l1 < m) ? l1 : 0);
      rc2 = RC; rc3 = RC;
    }
  }
  float a0s = 0.f, a1s = 0.f, a2s = 0.f, a3s = 0.f;

  // ---- phase B: double-buffered staging; single barrier per chunk ----
  float4 pf[SPT];
  float4 cpf;
#pragma unroll
  for (int k = 0; k < SPT; ++k){
    int e = tid + k * NT;
    if (e < nst){
      int r = e >> 5, j = e & 31;
      pf[k] = ((const float4*)(feat + (size_t)gid_s[r] * D_))[j];
    }
  }
  if (tid < CK/4) cpf = ((const float4*)(cent + (size_t)c * D_))[tid];
#pragma unroll
  for (int k = 0; k < SPT; ++k){
    int e = tid + k * NT;
    if (e < nst){
      int r = e >> 5, j = e & 31;
      ((float4*)&tile[r * SROW])[j] = pf[k];
    }
  }
  if (tid < CK/4) ((float4*)cvec[0])[tid] = cpf;
  __syncthreads();

  for (int ch = 0; ch < NCH; ++ch){
    const int cur = ch & 1;
    if (ch + 1 < NCH){
      const int d0 = (ch + 1) * CK;
#pragma unroll
      for (int k = 0; k < SPT; ++k){
        int e = tid + k * NT;
        if (e < nst){
          int r = e >> 5, j = e & 31;
          pf[k] = ((const float4*)(feat + (size_t)gid_s[r] * D_ + d0))[j];
        }
      }
      if (tid < CK/4) cpf = ((const float4*)(cent + (size_t)c * D_ + d0))[tid];
    }
    if (uty >= 0){
      const float* tl = tile + cur * TILE_F;
      const float4* cv4 = (const float4*)cvec[cur];
      const float4* A0 = (rc0 == RC) ? cv4 : (const float4*)&tl[rc0 * SROW];
      const float4* A1 = (rc1 == RC) ? cv4 : (const float4*)&tl[rc1 * SROW];
      const float4* Bp0 = (rc2 == RC) ? cv4 : (const float4*)&tl[rc2 * SROW];
      const float4* Bp1 = (rc3 == RC) ? cv4 : (const float4*)&tl[rc3 * SROW];
      float s00 = 0.f, s01 = 0.f, s10 = 0.f, s11 = 0.f;
#pragma unroll 8
      for (int j = 0; j < CK/4; ++j){
        float4 a0 = A0[j], a1 = A1[j], b0 = Bp0[j], b1 = Bp1[j];
        s00 += dot4(a0, b0); s01 += dot4(a0, b1);
        s10 += dot4(a1, b0); s11 += dot4(a1, b1);
      }
      a0s += s00; a1s += s01; a2s += s10; a3s += s11;
    }
    if (ch + 1 < NCH){
      float* tn = tile + (cur ^ 1) * TILE_F;
#pragma unroll
      for (int k = 0; k < SPT; ++k){
        int e = tid + k * NT;
        if (e < nst){
          int r = e >> 5, j = e & 31;
          ((float4*)&tn[r * SROW])[j] = pf[k];
        }
      }
      if (tid < CK/4) ((float4*)cvec[cur ^ 1])[tid] = cpf;
    }
    __syncthreads();
  }

  // owner-writes selfs/ecs/cn (diag+ec on both siblings, identical bits)
  if (uty == 1){
    selfs[ta_] = a0s;                           // self d (d < h <= m)
    if (ta_ + h < m) selfs[ta_ + h] = a3s;      // self d+h
  } else if (uty == 2){
    ecs[g_] = a0s;
    int l1 = g_ + hec;
    if (l1 == m) cn_sh = a2s;
    else if (l1 < m) ecs[l1] = a2s;
  }
  __syncthreads();
  if (tid < m){
    float rn  = 1.f / fmaxf(sqrtf(selfs[tid]), 1e-12f);
    float cno = 1.f / fmaxf(sqrtf(cn_sh), 1e-12f);
    selfs[tid] = rn;
    ecs[tid] = ecs[tid] * rn * cno;
  }
  __syncthreads();

  // ---- publish normalized S (R9 expression, same bits). Diag pair (d,d+h)
  // written identically by both siblings — benign. ----
  if (uty == 0){
    const int a1r = ta_ + h, b1r = tb_ + h;
    {   // (ta_, tb_): always valid (tb_ <= h-1 < m)
      float S = a0s * selfs[ta_]; S *= selfs[tb_];
      wsc[(ta_*(2*m - 1 - ta_))/2 + (tb_ - ta_ - 1)] = S;
    }
    if (b1r < m){
      float S = a1s * selfs[ta_]; S *= selfs[b1r];
      wsc[(ta_*(2*m - 1 - ta_))/2 + (b1r - ta_ - 1)] = S;
    }
    if (a1r < m){   // pair (tb_, a1r): tb_ < h <= a1r
      float S = a2s * selfs[tb_]; S *= selfs[a1r];
      wsc[(tb_*(2*m - 1 - tb_))/2 + (a1r - tb_ - 1)] = S;
    }
    if (a1r < m && b1r < m){
      float S = a3s * selfs[a1r]; S *= selfs[b1r];
      wsc[(a1r*(2*m - 1 - a1r))/2 + (b1r - a1r - 1)] = S;
    }
  } else if (uty == 1){
    const int d = ta_, l1 = ta_ + h;
    if (l1 < m){
      float S = a1s * selfs[d]; S *= selfs[l1];
      wsc[(d*(2*m - 1 - d))/2 + (l1 - d - 1)] = S;
    }
  }
  if (kh == 0 && tid < m) wsE[c * M_MAX + tid] = ecs[tid];
}

// ==== KERNEL 2: selection + loss consumer (grid 128). Reads m/gid/S/ecs
// from ws (stream-ordered after k_gram), rebuilds Sl/fidx (same bits), runs
// verified D-ballot + O(bin) list-select + p-strided E + R5 completion. ====
__global__ __launch_bounds__(NT) void k_sel(
    const float* __restrict__ feat, const float* __restrict__ cent,
    const int* __restrict__ labels,
    float* __restrict__ lossv, float* __restrict__ wv,
    unsigned* __restrict__ flags,
    const int* __restrict__ wsM, const int* __restrict__ wsG,
    const float* __restrict__ wsS, const float* __restrict__ wsE,
    float* __restrict__ out)
{
  const int c = blockIdx.x;
  const int tid = threadIdx.x;
  const int wid = tid >> 6, lane = tid & 63;

  __shared__ int   gid_s[M_MAX];
  __shared__ float Sl[P_MAX];                 // 18240 B
  __shared__ unsigned short fidx_s[P_MAX];    // 9120 B
  __shared__ float ecs[M_MAX];
  __shared__ int   wcnt[NW * 64];
  __shared__ int   B0_sh, ex_sh, B1_sh, ex2_sh;
  __shared__ float thr_sh;
  __shared__ float lst[LCAP];
  __shared__ int   listn;
  __shared__ float redbuf[2 * NW];
  __shared__ int   last_sh;

  const int m = wsM[c];          // published by k_gram (stream-ordered)

  float lloss = 0.f, lw = 0.f;

  if (m >= 2 && m <= M_MAX){
    const int P = m * (m - 1) / 2;
    const int k0 = (P - 1) >> 1;
    const float wc = (float)m;
    const float* wsc = wsS + (size_t)c * P_MAX;

    if (tid == 0) listn = 0;
    if (tid < m){
      gid_s[tid] = wsG[c * M_MAX + tid];
      ecs[tid]   = wsE[c * M_MAX + tid];
    }
    for (int p = tid; p < P; p += NT){
      float S = wsc[p];
      Sl[p] = S;
      float pd = 1.f - clamp1(S);               // in [0,2] exactly
      fidx_s[p] = (unsigned short)min(4095, (int)(pd * 2048.f));
    }
    __syncthreads();

    // ---- phase D: two-level ballot rank-select (R9 verbatim) ----
    const int nch = (P + NT - 1) / NT;
    int cl = 0;
    for (int t = 0; t < nch; ++t){
      int p = tid + t * NT;
      int bkt = -1;
      if (p < P) bkt = fidx_s[p] >> 6;
#pragma unroll
      for (int k = 0; k < 64; ++k){
        unsigned long long msk = __ballot(bkt == k);
        if (lane == k) cl += __popcll(msk);
      }
    }
    wcnt[wid*64 + lane] = cl;
    __syncthreads();
    if (tid < 64){
      int tot = 0;
#pragma unroll
      for (int w = 0; w < NW; ++w) tot += wcnt[w*64 + tid];
      int inc = tot;
#pragma unroll
      for (int o = 1; o < 64; o <<= 1){
        int v = __shfl_up(inc, o, 64);
        if (tid >= o) inc += v;
      }
      int excl = inc - tot;
      if (excl <= k0 && k0 < inc){ B0_sh = tid; ex_sh = excl; }
    }
    __syncthreads();
    const int Bsel0 = B0_sh;
    const int kt = k0 - ex_sh;
    cl = 0;
    for (int t = 0; t < nch; ++t){
      int p = tid + t * NT;
      int bkt = -1;
      if (p < P){
        int f = fidx_s[p];
        if ((f >> 6) == Bsel0) bkt = f & 63;
      }
#pragma unroll
      for (int k = 0; k < 64; ++k){
        unsigned long long msk = __ballot(bkt == k);
        if (lane == k) cl += __popcll(msk);
      }
    }
    wcnt[wid*64 + lane] = cl;
    __syncthreads();
    if (tid < 64){
      int tot = 0;
#pragma unroll
      for (int w = 0; w < NW; ++w) tot += wcnt[w*64 + tid];
      int inc = tot;
#pragma unroll
      for (int o = 1; o < 64; o <<= 1){
        int v = __shfl_up(inc, o, 64);
        if (tid >= o) inc += v;
      }
      int excl = inc - tot;
      if (excl <= kt && kt < inc){ B1_sh = tid; ex2_sh = excl; }
    }
    __syncthreads();
    const int fsel = (Bsel0 << 6) | B1_sh;
    const int ktf  = kt - ex2_sh;      // rank within the selected fine bin

    // candidates: p-strided append (expected ~7; order-independent select)
    for (int p = tid; p < P; p += NT){
      if (fidx_s[p] == (unsigned short)fsel){
        int ix = atomicAdd(&listn, 1);
        if (ix < LCAP) lst[ix] = 1.f - clamp1(Sl[p]);
      }
    }
    __syncthreads();
    const int ln = listn;
    if (ln <= LCAP){
      if (tid < ln){
        float pdp = lst[tid];
        int lt = 0, eq = 0;
        for (int j = 0; j < ln; ++j){
          float v = lst[j];
          lt += (v < pdp); eq += (v == pdp);
        }
        if (lt <= ktf && ktf < lt + eq) thr_sh = pdp;   // ties write same value
      }
    } else {
      // overflow fallback (unreachable for this data): full recount
      for (int p = tid; p < P; p += NT){
        if (fidx_s[p] == (unsigned short)fsel){
          float pdp = 1.f - clamp1(Sl[p]);
          int lt = 0, eq = 0;
          for (int q = 0; q < P; ++q){
            float pdq = 1.f - clamp1(Sl[q]);
            lt += (pdq < pdp); eq += (pdq == pdp);
          }
          if (lt <= k0 && k0 < lt + eq) thr_sh = pdp;
        }
      }
    }
    __syncthreads();
    const float thr = thr_sh;

    // ---- phase E: p-strided, byte-identical summation order (R9) ----
    for (int p = tid; p < P; p += NT){
      float S = Sl[p];
      float pd = 1.f - clamp1(S);
      if (pd > thr){
        int a, b; decode_pair(p, m, &a, &b);
        int ga = gid_s[a], gb = gid_s[b];
        float ea = ecs[a], eb = ecs[b];
        int i, j; float eci, ecj;
        if (ga < gb){ i = ga; j = gb; eci = ea; ecj = eb; }
        else        { i = gb; j = ga; eci = eb; ecj = ea; }
        float r = rand_ij((unsigned)i * (unsigned)B_ + (unsigned)j);
        float omr = 1.f - r;
        float n2 = r * r + omr * omr + 2.f * r * omr * S;    // raw (unclipped) S
        float nrm = fmaxf(sqrtf(fmaxf(n2, 0.f)), 1e-12f);
        float dt = clamp1((r * eci + omr * ecj) / nrm);
        lloss += wc * (1.f - dt);
        lw += wc;
      }
    }
  } else if (m > M_MAX){
    // correctness-only fallback (unreachable: all m<=96, verified)
    int* mem = (int*)Sl;                       // m <= 4096 ints fit in Sl
    if (tid == 0) B0_sh = 0;
    __syncthreads();
    for (int i = tid; i < B_; i += NT)
      if (labels[i] == c){ int p = atomicAdd(&B0_sh, 1); mem[p] = i; }
    __syncthreads();
    const int P = m * (m - 1) / 2;
    const int k0 = (P - 1) >> 1;
    const float wc = (float)m;
    const float* cc = cent + (size_t)c * D_;
    const float cno = 1.f / fmaxf(sqrtf(dotg(cc, cc)), 1e-12f);
    for (int p = tid; p < P; p += NT){
      int a, b; decode_pair(p, m, &a, &b);
      float pdp = 1.f - clamp1(S_pair_g(feat, mem[a], mem[b]));
      int lt = 0, eq = 0;
      for (int q = 0; q < P; ++q){
        int a2, b2; decode_pair(q, m, &a2, &b2);
        float pdq = 1.f - clamp1(S_pair_g(feat, mem[a2], mem[b2]));
        lt += (pdq < pdp); eq += (pdq == pdp);
      }
      if (lt <= k0 && k0 < lt + eq) thr_sh = pdp;
    }
    __syncthreads();
    const float thr = thr_sh;
    for (int p = tid; p < P; p += NT){
      int a, b; decode_pair(p, m, &a, &b);
      int ga = mem[a], gb = mem[b];
      float S = S_pair_g(feat, ga, gb);
      float pd = 1.f - clamp1(S);
      if (pd > thr){
        if (ga > gb){ int t2 = ga; ga = gb; gb = t2; }
        const float* ra = feat + (size_t)ga * D_;
        const float* rb = feat + (size_t)gb * D_;
        float eci = dotg(ra, cc) / fmaxf(sqrtf(dotg(ra, ra)), 1e-12f) * cno;
        float ecj = dotg(rb, cc) / fmaxf(sqrtf(dotg(rb, rb)), 1e-12f) * cno;
        float r = rand_ij((unsigned)ga * (unsigned)B_ + (unsigned)gb);
        float omr = 1.f - r;
        float n2 = r * r + omr * omr + 2.f * r * omr * S;
        float nrm = fmaxf(sqrtf(fmaxf(n2, 0.f)), 1e-12f);
        float dt = clamp1((r * eci + omr * ecj) / nrm);
        lloss += wc * (1.f - dt);
        lw += wc;
      }
    }
  }
  // m < 2: contributes zeros

  // ---- R5 last-arriver completion (HW-verified): publish partials, one
  // acq_rel counter RMW, exit; 128th arriver reduces. Init-agnostic. ----
  lloss = wave_red(lloss); lw = wave_red(lw);
  if (lane == 0){ redbuf[wid] = lloss; redbuf[NW + wid] = lw; }
  __syncthreads();
  if (tid == 0){
    float tl = 0.f, tw = 0.f;
#pragma unroll
    for (int i = 0; i < NW; ++i){ tl += redbuf[i]; tw += redbuf[NW + i]; }
    __hip_atomic_store(&lossv[c], tl, __ATOMIC_RELAXED, __HIP_MEMORY_SCOPE_AGENT);
    __hip_atomic_store(&wv[c],   tw, __ATOMIC_RELAXED, __HIP_MEMORY_SCOPE_AGENT);
    unsigned old = __hip_atomic_fetch_add(&flags[0], 1u, __ATOMIC_ACQ_REL,
                                          __HIP_MEMORY_SCOPE_AGENT);
    last_sh = ((old & 127u) == 127u) ? 1 : 0;
  }
  __syncthreads();
  if (last_sh){
    float lv = 0.f, wvv = 0.f;
    if (tid < C_){
      lv  = __hip_atomic_load(&lossv[tid], __ATOMIC_RELAXED, __HIP_MEMORY_SCOPE_AGENT);
      wvv = __hip_atomic_load(&wv[tid],   __ATOMIC_RELAXED, __HIP_MEMORY_SCOPE_AGENT);
    }
    lv = wave_red(lv); wvv = wave_red(wvv);
    if (lane == 0){ redbuf[wid] = lv; redbuf[NW + wid] = wvv; }
    __syncthreads();
    if (tid == 0){
      float l = redbuf[0] + redbuf[1];
      float w = redbuf[NW] + redbuf[NW + 1];
      out[0] = (w > 0.f) ? (l / w) : 0.f;
    }
  }
}

// ==== FALLBACK kernel: R9 verbatim (grid 128), used when ws too small ====
__global__ __launch_bounds__(NT) void k_all(
    const float* __restrict__ feat, const float* __restrict__ cent,
    const int* __restrict__ labels,
    float* __restrict__ lossv, float* __restrict__ wv,
    unsigned* __restrict__ flags, float* __restrict__ out)
{
  const int c = blockIdx.x;
  const int tid = threadIdx.x;
  const int wid = tid >> 6, lane = tid & 63;

  __shared__ int   gid_s[M_MAX];
  __shared__ int   mcount;
  __shared__ __align__(16) float tile[2 * TILE_F];
  __shared__ __align__(16) float cvec[2][CK];
  float*          Sl     = tile;
  unsigned short* fidx_s = (unsigned short*)(tile + P_MAX);
  __shared__ float selfs[M_MAX];
  __shared__ float ecs[M_MAX];
  __shared__ float cn_sh;
  __shared__ int   wcnt[NW * 64];
  __shared__ int   B0_sh, ex_sh, B1_sh, ex2_sh;
  __shared__ float thr_sh;
  __shared__ float lst[LCAP];
  __shared__ int   listn;
  __shared__ float redbuf[2 * NW];
  __shared__ int   last_sh;

  if (tid == 0) mcount = 0;
  __syncthreads();
  {
    const int4* lab4 = (const int4*)labels;
    for (int i = tid; i < B_ / 4; i += NT){
      int4 L = lab4[i];
      int base = i << 2;
      if (L.x == c){ int p = atomicAdd(&mcount, 1); if (p < M_MAX) gid_s[p] = base; }
      if (L.y == c){ int p = atomicAdd(&mcount, 1); if (p < M_MAX) gid_s[p] = base + 1; }
      if (L.z == c){ int p = atomicAdd(&mcount, 1); if (p < M_MAX) gid_s[p] = base + 2; }
      if (L.w == c){ int p = atomicAdd(&mcount, 1); if (p < M_MAX) gid_s[p] = base + 3; }
    }
  }
  __syncthreads();
  const int m = mcount;

  float lloss = 0.f, lw = 0.f;

  if (m >= 2 && m <= M_MAX){
    const int P = m * (m - 1) / 2;
    const int k0 = (P - 1) >> 1;
    const float wc = (float)m;
    const int nst = m * (CK / 4);

    const int h    = (m + 1) >> 1;
    const int Upair = h * (h + 1) / 2;
    const int hec  = (m + 2) >> 1;
    const int U    = Upair + hec;

    int c0[LM2], c1[LM2], c2[LM2], c3[LM2];
    int tAv[LM2], tBv[LM2];
    float acc[LM2][4];
    int nlay = 0;
#pragma unroll
    for (int t = 0; t < LM2; ++t){
      acc[t][0] = acc[t][1] = acc[t][2] = acc[t][3] = 0.f;
      c0[t] = c1[t] = c2[t] = c3[t] = 0; tAv[t] = 0; tBv[t] = -3;
      int u = tid + t * NT;
      if (u < U){
        nlay = t + 1;
        if (u < Upair){
          int ta = 0;
          while ((ta + 1) * h - ((ta + 1) * ta) / 2 <= u) ++ta;
          int tb = ta + (u - (ta * h - (ta * (ta - 1)) / 2));
          c0[t] = ta; c1[t] = ta + h; c2[t] = tb; c3[t] = tb + h;
          tAv[t] = ta; tBv[t] = tb;
        } else {
          int g = u - Upair;
          int l1 = g + hec;
          c0[t] = g;
          c1[t] = (l1 == m) ? RC : ((l1 < m) ? l1 : 0);
          c2[t] = RC; c3[t] = RC;
          tAv[t] = g; tBv[t] = -1;
        }
      }
    }

    float4 pf[SPT];
    float4 cpf;
#pragma unroll
    for (int k = 0; k < SPT; ++k){
      int e = tid + k * NT;
      if (e < nst){
        int r = e >> 5, j = e & 31;
        pf[k] = ((const float4*)(feat + (size_t)gid_s[r] * D_))[j];
      }
    }
    if (tid < CK/4) cpf = ((const float4*)(cent + (size_t)c * D_))[tid];
#pragma unroll
    for (int k = 0; k < SPT; ++k){
      int e = tid + k * NT;
      if (e < nst){
        int r = e >> 5, j = e & 31;
        ((float4*)&tile[r * SROW])[j] = pf[k];
      }
    }
    if (tid < CK/4) ((float4*)cvec[0])[tid] = cpf;
    __syncthreads();

    for (int ch = 0; ch < NCH; ++ch){
      const int cur = ch & 1;
      if (ch + 1 < NCH){
        const int d0 = (ch + 1) * CK;
#pragma unroll
        for (int k = 0; k < SPT; ++k){
          int e = tid + k * NT;
          if (e < nst){
            int r = e >> 5, j = e & 31;
            pf[k] = ((const float4*)(feat + (size_t)gid_s[r] * D_ + d0))[j];
          }
        }
        if (tid < CK/4) cpf = ((const float4*)(cent + (size_t)c * D_ + d0))[tid];
      }
      {
        const float* tl = tile + cur * TILE_F;
        const float4* cv4 = (const float4*)cvec[cur];
#pragma unroll
        for (int t = 0; t < LM2; ++t){
          if (t < nlay){
            const float4* A0 = (c0[t] == RC) ? cv4 : (const float4*)&tl[c0[t] * SROW];
            const float4* A1 = (c1[t] == RC) ? cv4 : (const float4*)&tl[c1[t] * SROW];
            const float4* Bp0 = (c2[t] == RC) ? cv4 : (const float4*)&tl[c2[t] * SROW];
            const float4* Bp1 = (c3[t] == RC) ? cv4 : (const float4*)&tl[c3[t] * SROW];
            float s00 = 0.f, s01 = 0.f, s10 = 0.f, s11 = 0.f;
#pragma unroll 8
            for (int j = 0; j < CK/4; ++j){
              float4 a0 = A0[j], a1 = A1[j], b0 = Bp0[j], b1 = Bp1[j];
              s00 += dot4(a0, b0); s01 += dot4(a0, b1);
              s10 += dot4(a1, b0); s11 += dot4(a1, b1);
            }
            acc[t][0] += s00; acc[t][1] += s01;
            acc[t][2] += s10; acc[t][3] += s11;
          }
        }
      }
      if (ch + 1 < NCH){
        float* tn = tile + (cur ^ 1) * TILE_F;
#pragma unroll
        for (int k = 0; k < SPT; ++k){
          int e = tid + k * NT;
          if (e < nst){
            int r = e >> 5, j = e & 31;
            ((float4*)&tn[r * SROW])[j] = pf[k];
          }
        }
        if (tid < CK/4) ((float4*)cvec[cur ^ 1])[tid] = cpf;
      }
      __syncthreads();
    }

#pragma unroll
    for (int t = 0; t < LM2; ++t){
      if (t < nlay){
        if (tBv[t] == -1){
          int g = tAv[t], l1 = g + hec;
          ecs[g] = acc[t][0];
          if (l1 == m) cn_sh = acc[t][2];
          else if (l1 < m) ecs[l1] = acc[t][2];
        } else if (tBv[t] >= 0){
          const int ta = tAv[t], tb = tBv[t];
          const int a1 = ta + h;
          if (ta == tb){
            if (ta < m) selfs[ta] = acc[t][0];
            if (a1 < m) selfs[a1] = acc[t][3];
          }
        }
      }
    }
    __syncthreads();
    if (tid == 0) listn = 0;
    if (tid < m){
      float rn  = 1.f / fmaxf(sqrtf(selfs[tid]), 1e-12f);
      float cno = 1.f / fmaxf(sqrtf(cn_sh), 1e-12f);
      selfs[tid] = rn;
      ecs[tid] = ecs[tid] * rn * cno;
    }
    __syncthreads();

    float pdq_[LM2][4];
    int   fq_[LM2][4];
#pragma unroll
    for (int t = 0; t < LM2; ++t){
#pragma unroll
      for (int s = 0; s < 4; ++s){ pdq_[t][s] = 0.f; fq_[t][s] = -1; }
      if (t < nlay && tBv[t] >= 0){
        const int ta = tAv[t], tb = tBv[t], a1 = ta + h, b1 = tb + h;
        const int  pa[4]  = { ta, ta, tb, a1 };
        const int  pb[4]  = { tb, b1, a1, b1 };
        const bool dif    = (ta != tb);
        const bool val[4] = { dif, b1 < m, dif && (a1 < m), dif && (a1 < m) && (b1 < m) };
#pragma unroll
        for (int s = 0; s < 4; ++s){
          if (val[s]){
            float S = acc[t][s] * selfs[pa[s]]; S *= selfs[pb[s]];
            float pd = 1.f - clamp1(S);
            int p = (pa[s] * (2*m - 1 - pa[s])) / 2 + (pb[s] - pa[s] - 1);
            Sl[p] = S;
            int f = min(4095, (int)(pd * 2048.f));
            fidx_s[p] = (unsigned short)f;
            pdq_[t][s] = pd; fq_[t][s] = f;
          }
        }
      }
    }
    __syncthreads();

    const int nch = (P + NT - 1) / NT;
    int cl = 0;
    for (int t = 0; t < nch; ++t){
      int p = tid + t * NT;
      int bkt = -1;
      if (p < P) bkt = fidx_s[p] >> 6;
#pragma unroll
      for (int k = 0; k < 64; ++k){
        unsigned long long msk = __ballot(bkt == k);
        if (lane == k) cl += __popcll(msk);
      }
    }
    wcnt[wid*64 + lane] = cl;
    __syncthreads();
    if (tid < 64){
      int tot = 0;
#pragma unroll
      for (int w = 0; w < NW; ++w) tot += wcnt[w*64 + tid];
      int inc = tot;
#pragma unroll
      for (int o = 1; o < 64; o <<= 1){
        int v = __shfl_up(inc, o, 64);
        if (tid >= o) inc += v;
      }
      int excl = inc - tot;
      if (excl <= k0 && k0 < inc){ B0_sh = tid; ex_sh = excl; }
    }
    __syncthreads();
    const int Bsel0 = B0_sh;
    const int kt = k0 - ex_sh;
    cl = 0;
    for (int t = 0; t < nch; ++t){
      int p = tid + t * NT;
      int bkt = -1;
      if (p < P){
        int f = fidx_s[p];
        if ((f >> 6) == Bsel0) bkt = f & 63;
      }
#pragma unroll
      for (int k = 0; k < 64; ++k){
        unsigned long long msk = __ballot(bkt == k);
        if (lane == k) cl += __popcll(msk);
      }
    }
    wcnt[wid*64 + lane] = cl;
    __syncthreads();
    if (tid < 64){
      int tot = 0;
#pragma unroll
      for (int w = 0; w < NW; ++w) tot += wcnt[w*64 + tid];
      int inc = tot;
#pragma unroll
      for (int o = 1; o < 64; o <<= 1){
        int v = __shfl_up(inc, o, 64);
        if (tid >= o) inc += v;
      }
      int excl = inc - tot;
      if (excl <= kt && kt < inc){ B1_sh = tid; ex2_sh = excl; }
    }
    __syncthreads();
    const int fsel = (Bsel0 << 6) | B1_sh;
    const int ktf  = kt - ex2_sh;

#pragma unroll
    for (int t = 0; t < LM2; ++t){
#pragma unroll
      for (int s = 0; s < 4; ++s){
        if (fq_[t][s] == fsel){
          int ix = atomicAdd(&listn, 1);
          if (ix < LCAP) lst[ix] = pdq_[t][s];
        }
      }
    }
    __syncthreads();
    const int ln = listn;
    if (ln <= LCAP){
      if (tid < ln){
        float pdp = lst[tid];
        int lt = 0, eq = 0;
        for (int j = 0; j < ln; ++j){
          float v = lst[j];
          lt += (v < pdp); eq += (v == pdp);
        }
        if (lt <= ktf && ktf < lt + eq) thr_sh = pdp;
      }
    } else {
      for (int p = tid; p < P; p += NT){
        if (fidx_s[p] == (unsigned short)fsel){
          float pdp = 1.f - clamp1(Sl[p]);
          int lt = 0, eq = 0;
          for (int q = 0; q < P; ++q){
            float pdq = 1.f - clamp1(Sl[q]);
            lt += (pdq < pdp); eq += (pdq == pdp);
          }
          if (lt <= k0 && k0 < lt + eq) thr_sh = pdp;
        }
      }
    }
    __syncthreads();
    const float thr = thr_sh;

    for (int p = tid; p < P; p += NT){
      float S = Sl[p];
      float pd = 1.f - clamp1(S);
      if (pd > thr){
        int a, b; decode_pair(p, m, &a, &b);
        int ga = gid_s[a], gb = gid_s[b];
        float ea = ecs[a], eb = ecs[b];
        int i, j; float eci, ecj;
        if (ga < gb){ i = ga; j = gb; eci = ea; ecj = eb; }
        else        { i = gb; j = ga; eci = eb; ecj = ea; }
        float r = rand_ij((unsigned)i * (unsigned)B_ + (unsigned)j);
        float omr = 1.f - r;
        float n2 = r * r + omr * omr + 2.f * r * omr * S;
        float nrm = fmaxf(sqrtf(fmaxf(n2, 0.f)), 1e-12f);
        float dt = clamp1((r * eci + omr * ecj) / nrm);
        lloss += wc * (1.f - dt);
        lw += wc;
      }
    }
  } else if (m > M_MAX){
    int* mem = (int*)Sl;
    if (tid == 0) B0_sh = 0;
    __syncthreads();
    for (int i = tid; i < B_; i += NT)
      if (labels[i] == c){ int p = atomicAdd(&B0_sh, 1); mem[p] = i; }
    __syncthreads();
    const int P = m * (m - 1) / 2;
    const int k0 = (P - 1) >> 1;
    const float wc = (float)m;
    const float* cc = cent + (size_t)c * D_;
    const float cno = 1.f / fmaxf(sqrtf(dotg(cc, cc)), 1e-12f);
    for (int p = tid; p < P; p += NT){
      int a, b; decode_pair(p, m, &a, &b);
      float pdp = 1.f - clamp1(S_pair_g(feat, mem[a], mem[b]));
      int lt = 0, eq = 0;
      for (int q = 0; q < P; ++q){
        int a2, b2; decode_pair(q, m, &a2, &b2);
        float pdq = 1.f - clamp1(S_pair_g(feat, mem[a2], mem[b2]));
        lt += (pdq < pdp); eq += (pdq == pdp);
      }
      if (lt <= k0 && k0 < lt + eq) thr_sh = pdp;
    }
    __syncthreads();
    const float thr = thr_sh;
    for (int p = tid; p < P; p += NT){
      int a, b; decode_pair(p, m, &a, &b);
      int ga = mem[a], gb = mem[b];
      float S = S_pair_g(feat, ga, gb);
      float pd = 1.f - clamp1(S);
      if (pd > thr){
        if (ga > gb){ int t2 = ga; ga = gb; gb = t2; }
        const float* ra = feat + (size_t)ga * D_;
        const float* rb = feat + (size_t)gb * D_;
        float eci = dotg(ra, cc) / fmaxf(sqrtf(dotg(ra, ra)), 1e-12f) * cno;
        float ecj = dotg(rb, cc) / fmaxf(sqrtf(dotg(rb, rb)), 1e-12f) * cno;
        float r = rand_ij((unsigned)ga * (unsigned)B_ + (unsigned)gb);
        float omr = 1.f - r;
        float n2 = r * r + omr * omr + 2.f * r * omr * S;
        float nrm = fmaxf(sqrtf(fmaxf(n2, 0.f)), 1e-12f);
        float dt = clamp1((r * eci + omr * ecj) / nrm);
        lloss += wc * (1.f - dt);
        lw += wc;
      }
    }
  }

  lloss = wave_red(lloss); lw = wave_red(lw);
  if (lane == 0){ redbuf[wid] = lloss; redbuf[NW + wid] = lw; }
  __syncthreads();
  if (tid == 0){
    float tl = 0.f, tw = 0.f;
#pragma unroll
    for (int i = 0; i < NW; ++i){ tl += redbuf[i]; tw += redbuf[NW + i]; }
    __hip_atomic_store(&lossv[c], tl, __ATOMIC_RELAXED, __HIP_MEMORY_SCOPE_AGENT);
    __hip_atomic_store(&wv[c],   tw, __ATOMIC_RELAXED, __HIP_MEMORY_SCOPE_AGENT);
    unsigned old = __hip_atomic_fetch_add(&flags[0], 1u, __ATOMIC_ACQ_REL,
                                          __HIP_MEMORY_SCOPE_AGENT);
    last_sh = ((old & 127u) == 127u) ? 1 : 0;
  }
  __syncthreads();
  if (last_sh){
    float lv = 0.f, wvv = 0.f;
    if (tid < C_){
      lv  = __hip_atomic_load(&lossv[tid], __ATOMIC_RELAXED, __HIP_MEMORY_SCOPE_AGENT);
      wvv = __hip_atomic_load(&wv[tid],   __ATOMIC_RELAXED, __HIP_MEMORY_SCOPE_AGENT);
    }
    lv = wave_red(lv); wvv = wave_red(wvv);
    if (lane == 0){ redbuf[wid] = lv; redbuf[NW + wid] = wvv; }
    __syncthreads();
    if (tid == 0){
      float l = redbuf[0] + redbuf[1];
      float w = redbuf[NW] + redbuf[NW + 1];
      out[0] = (w > 0.f) ? (l / w) : 0.f;
    }
  }
}

extern "C" void kernel_launch(void* const* d_in, const int* in_sizes, int n_in,
                              void* d_out, int out_size, void* d_ws, size_t ws_size,
                              hipStream_t stream)
{
  const float* feat   = (const float*)d_in[0];
  const float* cent   = (const float*)d_in[1];
  const int*   labels = (const int*)d_in[2];
  // d_in[3] = cam_ids: unused by the reference computation.

  char* ws = (char*)d_ws;
  float*    lossv = (float*)(ws + 0);      // 128 floats
  float*    wvv   = (float*)(ws + 512);    // 128 floats
  unsigned* flags = (unsigned*)(ws + 1024);// [0] completion counter (mod 128)
  int*      wsM   = (int*)(ws + WS_MOFF);  // per-class m
  int*      wsG   = (int*)(ws + WS_GOFF);  // per-class gid list
  float*    wsS   = (float*)(ws + WS_SOFF);             // C_ x P_MAX pair dots
  float*    wsE   = (float*)(ws + WS_SOFF + WS_SBYTES); // C_ x M_MAX ecs

  if (ws_size >= WS_NEED){
    // stream-ordered producer/consumer: plain global memory across the
    // kernel boundary (standard visibility), no intra-kernel joins.
    k_gram<<<2 * C_, NT, 0, stream>>>(feat, cent, labels, wsM, wsG, wsS, wsE);
    k_sel<<<C_, NT, 0, stream>>>(feat, cent, labels, lossv, wvv, flags,
                                 wsM, wsG, wsS, wsE, (float*)d_out);
  } else {
    k_all<<<C_, NT, 0, stream>>>(feat, cent, labels, lossv, wvv, flags,
                                 (float*)d_out);
  }
}

// Round 15
// 102.918 us; speedup vs baseline: 1.2061x; 1.2061x over previous
//
#include <hip/hip_runtime.h>

#define B_ 4096
#define C_ 128
#define D_ 768
#define NT 1024
#define NW (NT/64)                  // 16 waves
#define M_MAX 96
#define P_MAX (M_MAX*(M_MAX-1)/2)   // 4560
#define CK 128
#define NCH (D_/CK)                 // 6
#define SROW 132                    // chunked path row stride (floats)
#define TILE_F (M_MAX*SROW)         // 12672 floats per chunked buffer
#define LM2 2                       // chunked path: units per thread
#define RC 127                      // row code meaning "cvec"
#define SPT ((M_MAX*(CK/4) + NT - 1)/NT)    // 3 staging float4s per thread (chunked)
#define LCAP 64                     // in-bin candidate list cap (expected ~7)
// ---- fast path (m <= MCAP): whole class staged to LDS once ----
// MCAP=48 keeps total LDS at ~156.9 KB <= 157,696 B proven-safe ceiling
// (R14's 163.1 KB was within 700 B of the 163,840 B cap — possible launch
// failure; one-variable fix). m in (MCAP, M_MAX] -> chunked path (correct).
#define MCAP 48
#define SROWF 772                   // 768 + 4 pad; bank(row) = 4r mod 32 (8-group spread)
#define FLAT_F (MCAP*SROWF)         // 37056 floats
#define SHP_F (FLAT_F + 768)        // + full cvec = 37824 floats = 151296 B
#define SPTF 9                      // ceil(48*192/1024) staging float4s per thread

__device__ __forceinline__ float wave_red(float v){
#pragma unroll
  for (int o = 32; o > 0; o >>= 1) v += __shfl_down(v, o, 64);
  return v;
}
__device__ __forceinline__ float clamp1(float x){ return fminf(fmaxf(x, -1.f), 1.f); }
__device__ __forceinline__ unsigned rotl32(unsigned x, int r){ return (x << r) | (x >> (32 - r)); }
__device__ __forceinline__ float dot4(float4 a, float4 b){
  return fmaf(a.x, b.x, fmaf(a.y, b.y, fmaf(a.z, b.z, a.w * b.w)));
}

// jax.random.uniform(jax.random.key(1),(B,B)) element n: Threefry-2x32 key (0,1),
// counters split in halves. Bit-exact (verified: absmax 0.0 across all rounds).
__device__ float rand_ij(unsigned n){
  const unsigned half = (unsigned)B_ * (unsigned)B_ / 2u;
  unsigned c0, c1; bool hi;
  if (n < half){ c0 = n; c1 = n + half; hi = false; }
  else         { c0 = n - half; c1 = n; hi = true; }
  const unsigned K0 = 0u, K1 = 1u, K2 = 0x1BD11BDBu;
  unsigned x0 = c0 + K0, x1 = c1 + K1;
#define TFR(r) { x0 += x1; x1 = rotl32(x1, (r)); x1 ^= x0; }
  TFR(13) TFR(15) TFR(26) TFR(6)  x0 += K1; x1 += K2 + 1u;
  TFR(17) TFR(29) TFR(16) TFR(24) x0 += K2; x1 += K0 + 2u;
  TFR(13) TFR(15) TFR(26) TFR(6)  x0 += K0; x1 += K1 + 3u;
  TFR(17) TFR(29) TFR(16) TFR(24) x0 += K1; x1 += K2 + 4u;
  TFR(13) TFR(15) TFR(26) TFR(6)  x0 += K2; x1 += K0 + 5u;
#undef TFR
  unsigned bits = hi ? x1 : x0;
  return __uint_as_float((bits >> 9) | 0x3F800000u) - 1.0f;
}

// p -> (a,b), a<b<m, row-major upper-tri. before(a) = a*(2m-1-a)/2.
__device__ __forceinline__ void decode_pair(int p, int m, int* a_, int* b_){
  float fm = (float)(2*m - 1);
  int a = (int)((fm - sqrtf(fm*fm - 8.0f*(float)p)) * 0.5f);
  a = max(0, min(a, m - 2));
  while (a > 0 && (a*(2*m - 1 - a))/2 > p) --a;
  while (((a + 1)*(2*m - 2 - a))/2 <= p) ++a;
  *a_ = a;
  *b_ = a + 1 + (p - (a*(2*m - 1 - a))/2);
}

// ---- slow-path helpers (unreachable: all classes m<=96; insurance only) ----
__device__ float dotg(const float* x, const float* y){
  float s = 0.f;
  for (int k = 0; k < D_; ++k) s = fmaf(x[k], y[k], s);
  return s;
}
__device__ float S_pair_g(const float* feat, int ga, int gb){
  const float* ra = feat + (size_t)ga * D_;
  const float* rb = feat + (size_t)gb * D_;
  float d = dotg(ra, rb);
  float na = 1.f / fmaxf(sqrtf(dotg(ra, ra)), 1e-12f);
  float nb = 1.f / fmaxf(sqrtf(dotg(rb, rb)), 1e-12f);
  return d * na * nb;
}

// ==== single kernel (grid 128), R9 structure + FLAT fast path (m<=MCAP):
// whole class staged to LDS ONCE, one barrier, uninterrupted 2x2 gram with
// the identical two-level per-chunk fold (bit-exact vs R9). m in
// (MCAP, M_MAX]: R9 chunked path verbatim. Shared verified tail:
// ballot-D + O(bin) list select + p-strided E + R5 completion. ====
__global__ __launch_bounds__(NT) void k_all(
    const float* __restrict__ feat, const float* __restrict__ cent,
    const int* __restrict__ labels,
    float* __restrict__ lossv, float* __restrict__ wv,
    unsigned* __restrict__ flags, float* __restrict__ out)
{
  const int c = blockIdx.x;
  const int tid = threadIdx.x;
  const int wid = tid >> 6, lane = tid & 63;

  __shared__ int   gid_s[M_MAX];
  __shared__ int   mcount;
  __shared__ __align__(16) float shp[SHP_F];   // 151296 B union:
  // fast:    tileF = shp[0..FLAT_F), cvecF = shp+FLAT_F (768 floats)
  // chunked: tile  = shp[0..2*TILE_F), cvec2 = shp+2*TILE_F (2*CK floats)
  // overlay (both, after gram): Sl = shp[0..P_MAX), fidx = shp+P_MAX (ushort)
  float*          Sl     = shp;
  unsigned short* fidx_s = (unsigned short*)(shp + P_MAX);
  __shared__ float selfs[M_MAX];
  __shared__ float ecs[M_MAX];
  __shared__ float cn_sh;
  __shared__ int   wcnt[NW * 64];
  __shared__ int   B0_sh, ex_sh, B1_sh, ex2_sh;
  __shared__ float thr_sh;
  __shared__ float lst[LCAP];
  __shared__ int   listn;
  __shared__ float redbuf[2 * NW];
  __shared__ int   last_sh;

  // ---- phase A: collect members of class c (int4 label loads) ----
  if (tid == 0) mcount = 0;
  __syncthreads();
  {
    const int4* lab4 = (const int4*)labels;
    for (int i = tid; i < B_ / 4; i += NT){
      int4 L = lab4[i];
      int base = i << 2;
      if (L.x == c){ int p = atomicAdd(&mcount, 1); if (p < M_MAX) gid_s[p] = base; }
      if (L.y == c){ int p = atomicAdd(&mcount, 1); if (p < M_MAX) gid_s[p] = base + 1; }
      if (L.z == c){ int p = atomicAdd(&mcount, 1); if (p < M_MAX) gid_s[p] = base + 2; }
      if (L.w == c){ int p = atomicAdd(&mcount, 1); if (p < M_MAX) gid_s[p] = base + 3; }
    }
  }
  __syncthreads();
  const int m = mcount;

  float lloss = 0.f, lw = 0.f;

  if (m >= 2 && m <= M_MAX){
    const int P = m * (m - 1) / 2;
    const int k0 = (P - 1) >> 1;
    const float wc = (float)m;
    const int h    = (m + 1) >> 1;
    const int hec  = (m + 2) >> 1;

    if (m <= MCAP){
      // ================= FAST PATH: flat single-stage =================
      const int Upair = h * (h + 1) / 2;
      const int U = Upair + hec;
      int uty = -1, ta_ = 0, tb_ = 0, g_ = 0;
      int rc0 = 0, rc1 = 0, rc2 = 0, rc3 = 0;
      if (tid < U){
        if (tid < Upair){
          int ta = 0;     // triangular incl. diagonal: before(ta)=ta*h-ta(ta-1)/2
          while ((ta + 1) * h - ((ta + 1) * ta) / 2 <= tid) ++ta;
          int tb = ta + (tid - (ta * h - (ta * (ta - 1)) / 2));
          uty = 0; ta_ = ta; tb_ = tb;
          rc0 = ta; rc1 = ta + h; rc2 = tb; rc3 = tb + h;
        } else {
          int g = tid - Upair, l1 = g + hec;
          uty = 2; g_ = g;
          rc0 = g;
          rc1 = (l1 == m) ? RC : ((l1 < m) ? l1 : 0);
          rc2 = RC; rc3 = RC;
        }
      }

      // bulk stage: all m rows (192 float4 each) + full cvec, reg-staged
      const int nstF = m * 192;
      float4 st[SPTF];
      float4 cvf;
#pragma unroll
      for (int k = 0; k < SPTF; ++k){
        int e = tid + k * NT;
        if (e < nstF){
          int r = e / 192, j = e - r * 192;
          st[k] = ((const float4*)(feat + (size_t)gid_s[r] * D_))[j];
        }
      }
      if (tid < 192) cvf = ((const float4*)(cent + (size_t)c * D_))[tid];
#pragma unroll
      for (int k = 0; k < SPTF; ++k){
        int e = tid + k * NT;
        if (e < nstF){
          int r = e / 192, j = e - r * 192;
          ((float4*)&shp[r * SROWF])[j] = st[k];
        }
      }
      if (tid < 192) ((float4*)(shp + FLAT_F))[tid] = cvf;
      __syncthreads();

      // uninterrupted gram; identical two-level fold (s per chunk, acc += s)
      float a0s = 0.f, a1s = 0.f, a2s = 0.f, a3s = 0.f;
      if (uty >= 0){
        const float4* cv4 = (const float4*)(shp + FLAT_F);
        const float4* A0 = (rc0 == RC) ? cv4 : (const float4*)&shp[rc0 * SROWF];
        const float4* A1 = (rc1 == RC) ? cv4 : (const float4*)&shp[rc1 * SROWF];
        const float4* Bp0 = (rc2 == RC) ? cv4 : (const float4*)&shp[rc2 * SROWF];
        const float4* Bp1 = (rc3 == RC) ? cv4 : (const float4*)&shp[rc3 * SROWF];
        for (int ch = 0; ch < NCH; ++ch){
          const int q0 = ch * 32;
          float s00 = 0.f, s01 = 0.f, s10 = 0.f, s11 = 0.f;
#pragma unroll 8
          for (int j = 0; j < 32; ++j){
            float4 a0 = A0[q0 + j], a1 = A1[q0 + j];
            float4 b0 = Bp0[q0 + j], b1 = Bp1[q0 + j];
            s00 += dot4(a0, b0); s01 += dot4(a0, b1);
            s10 += dot4(a1, b0); s11 += dot4(a1, b1);
          }
          a0s += s00; a1s += s01; a2s += s10; a3s += s11;
        }
      }

      // combine: selfs/ecs/cn (same mapping as R9)
      if (uty == 0){
        if (ta_ == tb_){
          if (ta_ < m) selfs[ta_] = a0s;
          if (ta_ + h < m) selfs[ta_ + h] = a3s;
        }
      } else if (uty == 2){
        ecs[g_] = a0s;
        int l1 = g_ + hec;
        if (l1 == m) cn_sh = a2s;
        else if (l1 < m) ecs[l1] = a2s;
      }
      __syncthreads();
      if (tid == 0) listn = 0;
      if (tid < m){
        float rn  = 1.f / fmaxf(sqrtf(selfs[tid]), 1e-12f);
        float cno = 1.f / fmaxf(sqrtf(cn_sh), 1e-12f);
        selfs[tid] = rn;
        ecs[tid] = ecs[tid] * rn * cno;
      }
      __syncthreads();

      // registerized C: S/pd/f from acc; write Sl + fidx (overlay; gram done)
      if (uty == 0){
        const int a1r = ta_ + h, b1r = tb_ + h;
        const bool dif = (ta_ != tb_);
        if (dif){
          float S = a0s * selfs[ta_]; S *= selfs[tb_];
          float pd = 1.f - clamp1(S);
          int p = (ta_*(2*m - 1 - ta_))/2 + (tb_ - ta_ - 1);
          Sl[p] = S; fidx_s[p] = (unsigned short)min(4095, (int)(pd * 2048.f));
        }
        if (b1r < m){
          float S = a1s * selfs[ta_]; S *= selfs[b1r];
          float pd = 1.f - clamp1(S);
          int p = (ta_*(2*m - 1 - ta_))/2 + (b1r - ta_ - 1);
          Sl[p] = S; fidx_s[p] = (unsigned short)min(4095, (int)(pd * 2048.f));
        }
        if (dif && a1r < m){
          float S = a2s * selfs[tb_]; S *= selfs[a1r];
          float pd = 1.f - clamp1(S);
          int p = (tb_*(2*m - 1 - tb_))/2 + (a1r - tb_ - 1);
          Sl[p] = S; fidx_s[p] = (unsigned short)min(4095, (int)(pd * 2048.f));
        }
        if (dif && a1r < m && b1r < m){
          float S = a3s * selfs[a1r]; S *= selfs[b1r];
          float pd = 1.f - clamp1(S);
          int p = (a1r*(2*m - 1 - a1r))/2 + (b1r - a1r - 1);
          Sl[p] = S; fidx_s[p] = (unsigned short)min(4095, (int)(pd * 2048.f));
        }
      }
      __syncthreads();
    } else {
      // ================= CHUNKED PATH (R9 verbatim; m in (MCAP, M_MAX]) ====
      const int nst = m * (CK / 4);
      float* tile = shp;
      float (*cvec)[CK] = (float(*)[CK])(shp + 2 * TILE_F);
      const int Upair = h * (h + 1) / 2;
      const int U = Upair + hec;

      int c0[LM2], c1[LM2], c2[LM2], c3[LM2];
      int tAv[LM2], tBv[LM2];
      float acc[LM2][4];
      int nlay = 0;
#pragma unroll
      for (int t = 0; t < LM2; ++t){
        acc[t][0] = acc[t][1] = acc[t][2] = acc[t][3] = 0.f;
        c0[t] = c1[t] = c2[t] = c3[t] = 0; tAv[t] = 0; tBv[t] = -3;
        int u = tid + t * NT;
        if (u < U){
          nlay = t + 1;
          if (u < Upair){
            int ta = 0;
            while ((ta + 1) * h - ((ta + 1) * ta) / 2 <= u) ++ta;
            int tb = ta + (u - (ta * h - (ta * (ta - 1)) / 2));
            c0[t] = ta; c1[t] = ta + h; c2[t] = tb; c3[t] = tb + h;
            tAv[t] = ta; tBv[t] = tb;
          } else {
            int g = u - Upair;
            int l1 = g + hec;
            c0[t] = g;
            c1[t] = (l1 == m) ? RC : ((l1 < m) ? l1 : 0);
            c2[t] = RC; c3[t] = RC;
            tAv[t] = g; tBv[t] = -1;
          }
        }
      }

      float4 pf[SPT];
      float4 cpf;
#pragma unroll
      for (int k = 0; k < SPT; ++k){
        int e = tid + k * NT;
        if (e < nst){
          int r = e >> 5, j = e & 31;
          pf[k] = ((const float4*)(feat + (size_t)gid_s[r] * D_))[j];
        }
      }
      if (tid < CK/4) cpf = ((const float4*)(cent + (size_t)c * D_))[tid];
#pragma unroll
      for (int k = 0; k < SPT; ++k){
        int e = tid + k * NT;
        if (e < nst){
          int r = e >> 5, j = e & 31;
          ((float4*)&tile[r * SROW])[j] = pf[k];
        }
      }
      if (tid < CK/4) ((float4*)cvec[0])[tid] = cpf;
      __syncthreads();

      for (int ch = 0; ch < NCH; ++ch){
        const int cur = ch & 1;
        if (ch + 1 < NCH){
          const int d0 = (ch + 1) * CK;
#pragma unroll
          for (int k = 0; k < SPT; ++k){
            int e = tid + k * NT;
            if (e < nst){
              int r = e >> 5, j = e & 31;
              pf[k] = ((const float4*)(feat + (size_t)gid_s[r] * D_ + d0))[j];
            }
          }
          if (tid < CK/4) cpf = ((const float4*)(cent + (size_t)c * D_ + d0))[tid];
        }
        {
          const float* tl = tile + cur * TILE_F;
          const float4* cv4 = (const float4*)cvec[cur];
#pragma unroll
          for (int t = 0; t < LM2; ++t){
            if (t < nlay){
              const float4* A0 = (c0[t] == RC) ? cv4 : (const float4*)&tl[c0[t] * SROW];
              const float4* A1 = (c1[t] == RC) ? cv4 : (const float4*)&tl[c1[t] * SROW];
              const float4* Bp0 = (c2[t] == RC) ? cv4 : (const float4*)&tl[c2[t] * SROW];
              const float4* Bp1 = (c3[t] == RC) ? cv4 : (const float4*)&tl[c3[t] * SROW];
              float s00 = 0.f, s01 = 0.f, s10 = 0.f, s11 = 0.f;
#pragma unroll 8
              for (int j = 0; j < CK/4; ++j){
                float4 a0 = A0[j], a1 = A1[j], b0 = Bp0[j], b1 = Bp1[j];
                s00 += dot4(a0, b0); s01 += dot4(a0, b1);
                s10 += dot4(a1, b0); s11 += dot4(a1, b1);
              }
              acc[t][0] += s00; acc[t][1] += s01;
              acc[t][2] += s10; acc[t][3] += s11;
            }
          }
        }
        if (ch + 1 < NCH){
          float* tn = tile + (cur ^ 1) * TILE_F;
#pragma unroll
          for (int k = 0; k < SPT; ++k){
            int e = tid + k * NT;
            if (e < nst){
              int r = e >> 5, j = e & 31;
              ((float4*)&tn[r * SROW])[j] = pf[k];
            }
          }
          if (tid < CK/4) ((float4*)cvec[cur ^ 1])[tid] = cpf;
        }
        __syncthreads();
      }

#pragma unroll
      for (int t = 0; t < LM2; ++t){
        if (t < nlay){
          if (tBv[t] == -1){
            int g = tAv[t], l1 = g + hec;
            ecs[g] = acc[t][0];
            if (l1 == m) cn_sh = acc[t][2];
            else if (l1 < m) ecs[l1] = acc[t][2];
          } else if (tBv[t] >= 0){
            const int ta = tAv[t], tb = tBv[t];
            const int a1 = ta + h;
            if (ta == tb){
              if (ta < m) selfs[ta] = acc[t][0];
              if (a1 < m) selfs[a1] = acc[t][3];
            }
          }
        }
      }
      __syncthreads();
      if (tid == 0) listn = 0;
      if (tid < m){
        float rn  = 1.f / fmaxf(sqrtf(selfs[tid]), 1e-12f);
        float cno = 1.f / fmaxf(sqrtf(cn_sh), 1e-12f);
        selfs[tid] = rn;
        ecs[tid] = ecs[tid] * rn * cno;
      }
      __syncthreads();

#pragma unroll
      for (int t = 0; t < LM2; ++t){
        if (t < nlay && tBv[t] >= 0){
          const int ta = tAv[t], tb = tBv[t], a1 = ta + h, b1 = tb + h;
          const int  pa[4]  = { ta, ta, tb, a1 };
          const int  pb[4]  = { tb, b1, a1, b1 };
          const bool dif    = (ta != tb);
          const bool val[4] = { dif, b1 < m, dif && (a1 < m), dif && (a1 < m) && (b1 < m) };
#pragma unroll
          for (int s = 0; s < 4; ++s){
            if (val[s]){
              float S = acc[t][s] * selfs[pa[s]]; S *= selfs[pb[s]];
              float pd = 1.f - clamp1(S);
              int p = (pa[s] * (2*m - 1 - pa[s])) / 2 + (pb[s] - pa[s] - 1);
              Sl[p] = S;
              fidx_s[p] = (unsigned short)min(4095, (int)(pd * 2048.f));
            }
          }
        }
      }
      __syncthreads();
    }

    // ======= shared verified tail: ballot-D + list select + E =======
    const int nch = (P + NT - 1) / NT;
    int cl = 0;
    for (int t = 0; t < nch; ++t){
      int p = tid + t * NT;
      int bkt = -1;
      if (p < P) bkt = fidx_s[p] >> 6;
#pragma unroll
      for (int k = 0; k < 64; ++k){
        unsigned long long msk = __ballot(bkt == k);
        if (lane == k) cl += __popcll(msk);
      }
    }
    wcnt[wid*64 + lane] = cl;
    __syncthreads();
    if (tid < 64){
      int tot = 0;
#pragma unroll
      for (int w = 0; w < NW; ++w) tot += wcnt[w*64 + tid];
      int inc = tot;
#pragma unroll
      for (int o = 1; o < 64; o <<= 1){
        int v = __shfl_up(inc, o, 64);
        if (tid >= o) inc += v;
      }
      int excl = inc - tot;
      if (excl <= k0 && k0 < inc){ B0_sh = tid; ex_sh = excl; }
    }
    __syncthreads();
    const int Bsel0 = B0_sh;
    const int kt = k0 - ex_sh;
    cl = 0;
    for (int t = 0; t < nch; ++t){
      int p = tid + t * NT;
      int bkt = -1;
      if (p < P){
        int f = fidx_s[p];
        if ((f >> 6) == Bsel0) bkt = f & 63;
      }
#pragma unroll
      for (int k = 0; k < 64; ++k){
        unsigned long long msk = __ballot(bkt == k);
        if (lane == k) cl += __popcll(msk);
      }
    }
    wcnt[wid*64 + lane] = cl;
    __syncthreads();
    if (tid < 64){
      int tot = 0;
#pragma unroll
      for (int w = 0; w < NW; ++w) tot += wcnt[w*64 + tid];
      int inc = tot;
#pragma unroll
      for (int o = 1; o < 64; o <<= 1){
        int v = __shfl_up(inc, o, 64);
        if (tid >= o) inc += v;
      }
      int excl = inc - tot;
      if (excl <= kt && kt < inc){ B1_sh = tid; ex2_sh = excl; }
    }
    __syncthreads();
    const int fsel = (Bsel0 << 6) | B1_sh;
    const int ktf  = kt - ex2_sh;      // rank within selected fine bin

    // candidates: p-strided append (verified R12/R13; order-independent)
    for (int p = tid; p < P; p += NT){
      if (fidx_s[p] == (unsigned short)fsel){
        int ix = atomicAdd(&listn, 1);
        if (ix < LCAP) lst[ix] = 1.f - clamp1(Sl[p]);
      }
    }
    __syncthreads();
    const int ln = listn;
    if (ln <= LCAP){
      if (tid < ln){
        float pdp = lst[tid];
        int lt = 0, eq = 0;
        for (int j = 0; j < ln; ++j){
          float v = lst[j];
          lt += (v < pdp); eq += (v == pdp);
        }
        if (lt <= ktf && ktf < lt + eq) thr_sh = pdp;   // ties write same value
      }
    } else {
      // overflow fallback (unreachable for this data): full recount
      for (int p = tid; p < P; p += NT){
        if (fidx_s[p] == (unsigned short)fsel){
          float pdp = 1.f - clamp1(Sl[p]);
          int lt = 0, eq = 0;
          for (int q = 0; q < P; ++q){
            float pdq = 1.f - clamp1(Sl[q]);
            lt += (pdq < pdp); eq += (pdq == pdp);
          }
          if (lt <= k0 && k0 < lt + eq) thr_sh = pdp;
        }
      }
    }
    __syncthreads();
    const float thr = thr_sh;

    // phase E: p-strided, byte-identical summation order (R9)
    for (int p = tid; p < P; p += NT){
      float S = Sl[p];
      float pd = 1.f - clamp1(S);
      if (pd > thr){
        int a, b; decode_pair(p, m, &a, &b);
        int ga = gid_s[a], gb = gid_s[b];
        float ea = ecs[a], eb = ecs[b];
        int i, j; float eci, ecj;
        if (ga < gb){ i = ga; j = gb; eci = ea; ecj = eb; }
        else        { i = gb; j = ga; eci = eb; ecj = ea; }
        float r = rand_ij((unsigned)i * (unsigned)B_ + (unsigned)j);
        float omr = 1.f - r;
        float n2 = r * r + omr * omr + 2.f * r * omr * S;    // raw (unclipped) S
        float nrm = fmaxf(sqrtf(fmaxf(n2, 0.f)), 1e-12f);
        float dt = clamp1((r * eci + omr * ecj) / nrm);
        lloss += wc * (1.f - dt);
        lw += wc;
      }
    }
  } else if (m > M_MAX){
    // correctness-only fallback (unreachable: all m<=96, verified)
    int* mem = (int*)Sl;
    if (tid == 0) B0_sh = 0;
    __syncthreads();
    for (int i = tid; i < B_; i += NT)
      if (labels[i] == c){ int p = atomicAdd(&B0_sh, 1); mem[p] = i; }
    __syncthreads();
    const int P = m * (m - 1) / 2;
    const int k0 = (P - 1) >> 1;
    const float wc = (float)m;
    const float* cc = cent + (size_t)c * D_;
    const float cno = 1.f / fmaxf(sqrtf(dotg(cc, cc)), 1e-12f);
    for (int p = tid; p < P; p += NT){
      int a, b; decode_pair(p, m, &a, &b);
      float pdp = 1.f - clamp1(S_pair_g(feat, mem[a], mem[b]));
      int lt = 0, eq = 0;
      for (int q = 0; q < P; ++q){
        int a2, b2; decode_pair(q, m, &a2, &b2);
        float pdq = 1.f - clamp1(S_pair_g(feat, mem[a2], mem[b2]));
        lt += (pdq < pdp); eq += (pdq == pdp);
      }
      if (lt <= k0 && k0 < lt + eq) thr_sh = pdp;
    }
    __syncthreads();
    const float thr = thr_sh;
    for (int p = tid; p < P; p += NT){
      int a, b; decode_pair(p, m, &a, &b);
      int ga = mem[a], gb = mem[b];
      float S = S_pair_g(feat, ga, gb);
      float pd = 1.f - clamp1(S);
      if (pd > thr){
        if (ga > gb){ int t2 = ga; ga = gb; gb = t2; }
        const float* ra = feat + (size_t)ga * D_;
        const float* rb = feat + (size_t)gb * D_;
        float eci = dotg(ra, cc) / fmaxf(sqrtf(dotg(ra, ra)), 1e-12f) * cno;
        float ecj = dotg(rb, cc) / fmaxf(sqrtf(dotg(rb, rb)), 1e-12f) * cno;
        float r = rand_ij((unsigned)ga * (unsigned)B_ + (unsigned)gb);
        float omr = 1.f - r;
        float n2 = r * r + omr * omr + 2.f * r * omr * S;
        float nrm = fmaxf(sqrtf(fmaxf(n2, 0.f)), 1e-12f);
        float dt = clamp1((r * eci + omr * ecj) / nrm);
        lloss += wc * (1.f - dt);
        lw += wc;
      }
    }
  }
  // m < 2: contributes zeros

  // ---- R5 last-arriver completion (HW-verified): publish partials, one
  // acq_rel counter RMW, exit; 128th arriver reduces. Init-agnostic. ----
  lloss = wave_red(lloss); lw = wave_red(lw);
  if (lane == 0){ redbuf[wid] = lloss; redbuf[NW + wid] = lw; }
  __syncthreads();
  if (tid == 0){
    float tl = 0.f, tw = 0.f;
#pragma unroll
    for (int i = 0; i < NW; ++i){ tl += redbuf[i]; tw += redbuf[NW + i]; }
    __hip_atomic_store(&lossv[c], tl, __ATOMIC_RELAXED, __HIP_MEMORY_SCOPE_AGENT);
    __hip_atomic_store(&wv[c],   tw, __ATOMIC_RELAXED, __HIP_MEMORY_SCOPE_AGENT);
    unsigned old = __hip_atomic_fetch_add(&flags[0], 1u, __ATOMIC_ACQ_REL,
                                          __HIP_MEMORY_SCOPE_AGENT);
    last_sh = ((old & 127u) == 127u) ? 1 : 0;
  }
  __syncthreads();
  if (last_sh){
    float lv = 0.f, wvv = 0.f;
    if (tid < C_){
      lv  = __hip_atomic_load(&lossv[tid], __ATOMIC_RELAXED, __HIP_MEMORY_SCOPE_AGENT);
      wvv = __hip_atomic_load(&wv[tid],   __ATOMIC_RELAXED, __HIP_MEMORY_SCOPE_AGENT);
    }
    lv = wave_red(lv); wvv = wave_red(wvv);
    if (lane == 0){ redbuf[wid] = lv; redbuf[NW + wid] = wvv; }
    __syncthreads();
    if (tid == 0){
      float l = redbuf[0] + redbuf[1];
      float w = redbuf[NW] + redbuf[NW + 1];
      out[0] = (w > 0.f) ? (l / w) : 0.f;
    }
  }
}

extern "C" void kernel_launch(void* const* d_in, const int* in_sizes, int n_in,
                              void* d_out, int out_size, void* d_ws, size_t ws_size,
                              hipStream_t stream)
{
  const float* feat   = (const float*)d_in[0];
  const float* cent   = (const float*)d_in[1];
  const int*   labels = (const int*)d_in[2];
  // d_in[3] = cam_ids: unused by the reference computation.

  char* ws = (char*)d_ws;
  float*    lossv = (float*)(ws + 0);      // 128 floats
  float*    wvv   = (float*)(ws + 512);    // 128 floats
  unsigned* flags = (unsigned*)(ws + 1024);// [0] completion counter (mod 128)

  // single graph node: no memset needed (kernel is init-agnostic on ws)
  k_all<<<C_, NT, 0, stream>>>(feat, cent, labels, lossv, wvv, flags, (float*)d_out);
}